// Round 8
// baseline (331.059 us; speedup 1.0000x reference)
//
#include <hip/hip_runtime.h>

// Problem constants (fixed by the reference): E=8, M=32768, K=1024, N=1024
#define M_DIM 32768
#define K_DIM 1024
#define N_DIM 1024
#define E_NUM 8

#define BM 128
#define BN 128
#define BK 128            // k-bytes staged per step (full 128B cache lines)
#define KSTEPS (K_DIM / BK)   // 8

typedef __attribute__((ext_vector_type(4))) int v4i;

// ---------------------------------------------------------------------------
// Pass 1a: pack x (int32 valued int8) -> int8 [M][K].  (round-7 known-good)
// ---------------------------------------------------------------------------
__global__ __launch_bounds__(256) void pack_x_kernel(const int4* __restrict__ x,
                                                     int* __restrict__ xq) {
    const int base = blockIdx.x * 1024 + (threadIdx.x >> 6) * 256 + (threadIdx.x & 63);
#pragma unroll
    for (int k = 0; k < 4; ++k) {
        const int4 a = x[base + k * 64];
        xq[base + k * 64] =
            (a.x & 255) | ((a.y & 255) << 8) | ((a.z & 255) << 16) | (a.w << 24);
    }
}

// ---------------------------------------------------------------------------
// Pass 1b: pack + transpose weight [E][K][N] int32 -> [E][N][K] int8.
// (round-7 known-good)
// ---------------------------------------------------------------------------
__global__ __launch_bounds__(256) void pack_wt_kernel(const int* __restrict__ w,
                                                      int* __restrict__ wt) {
    __shared__ signed char tile[64][260];   // [n][k], +4 pad keeps banks spread
    const int e    = blockIdx.z;
    const int n0   = blockIdx.x * 64;
    const int k0   = blockIdx.y * 256;
    const int tid  = threadIdx.x;
    const int lane = tid & 63;
    const int wv   = tid >> 6;

    const int* wp = w + ((size_t)e << 20);
#pragma unroll 4
    for (int i = 0; i < 64; ++i) {
        const int k = wv * 64 + i;          // each wave: 64 k-rows
        tile[lane][k] = (signed char)wp[(size_t)(k0 + k) * N_DIM + n0 + lane];
    }
    __syncthreads();

    int* wo = wt + ((size_t)e << 18);       // int units: 1MB/4 per expert
#pragma unroll
    for (int i = 0; i < 16; ++i) {
        const int n = i * 4 + wv;
        const int v = *(const int*)&tile[n][lane * 4];   // 260 % 4 == 0, aligned
        wo[(size_t)(n0 + n) * (K_DIM / 4) + (k0 >> 2) + lane] = v;
    }
}

// ---------------------------------------------------------------------------
// Pass 2: grouped int8 GEMM + fused dequant.
// Round-8 change: SINGLE-barrier K-step. Per step:
//   [frag ds_reads; 32 MFMA; s_waitcnt vmcnt(0) lgkmcnt(0); barrier;
//    stage(t+2)]
// The one barrier certifies BOTH (a) all waves done reading buf[cur]
// (lgkm drained pre-barrier) so post-barrier stage(t+2) may overwrite it,
// and (b) all waves' stage(t+1) landed (vmcnt(0) pre-barrier: only
// stage(t+1) is outstanding there, stage(t+2) is issued post-barrier).
// Coverage of stage(t+1) = one compute phase, identical to round-2's
// counted-vmcnt form. Barriers/expert: 19 -> 9.
// Epilogue: direct dequant stores (round-0-proven): drops the LDS bounce's
// 2 barriers + 1.08M bank conflicts (WRITE_SIZE measured identical), and
// removes the need for any end-of-expert barrier (no LDS after the loop;
// in-order vmcnt retirement keeps the next prologue vmcnt(8) safe).
// ---------------------------------------------------------------------------
__global__ __launch_bounds__(256, 2) void gmm_kernel(
    const signed char* __restrict__ xq,    // [M][K] int8
    const signed char* __restrict__ wtq,   // [E][N][K] int8
    const float* __restrict__ scale,       // [E][N]
    const float* __restrict__ pts,         // [M]
    const int* __restrict__ g32,           // group_list viewed as int32
    float* __restrict__ out)               // [M][N] fp32
{
    // A(b) = smem + b*16KB, B(b) = smem + 32KB + b*16KB
    __shared__ signed char smem[65536];

    const int tid  = threadIdx.x;
    const int lane = tid & 63;
    const int wv   = tid >> 6;             // wave 0..3
    const int gid  = blockIdx.x;

    // XCD-stripe mapping: xcd = gid&7 owns contiguous 4096 m-rows, n inner
    // -> per-XCD A working set 4MB (L2-resident). FETCH 166->58MB confirmed.
    const int xcd   = gid & 7;
    const int local = gid >> 3;
    const int m0    = (xcd * 32 + (local >> 3)) * BM;
    const int n0    = (local & 7) * BN;

    // group_list (dtype-robust)
    const bool g_is_i64 = (g32[7] != M_DIM);
    int cum[E_NUM];
#pragma unroll
    for (int e = 0; e < E_NUM; ++e)
        cum[e] = g_is_i64 ? g32[2 * e] : g32[e];
    int e0 = 0;
    while (e0 < E_NUM - 1 && cum[e0] <= m0) ++e0;
    int e1 = 0;
    while (e1 < E_NUM - 1 && cum[e1] <= m0 + BM - 1) ++e1;

    const int wm    = (wv >> 1) * 64;
    const int wn    = (wv & 1) * 64;
    const int row_a = lane & 15;
    const int quad  = lane >> 4;
    const int rx    = row_a & 7;           // row&7 for all frag rows

    // staging lane geometry: chunk = 8 rows x 128B = 1KB, XOR-swizzled slots
    const int st_r = lane >> 3;                     // row in chunk 0..7
    const int st_c = ((lane & 7) ^ st_r) * 16;      // swizzled col bytes

    const signed char* xg = xq + (size_t)m0 * K_DIM;

    for (int e = e0; e <= e1; ++e) {
        const int lo = (e == 0) ? 0 : cum[e - 1];
        const int hi = cum[e];
        if (hi <= lo) continue;            // block-uniform
        const int slo = lo > m0 ? lo : m0;
        const int shi = hi < m0 + BM ? hi : m0 + BM;
        if (slo >= shi) continue;

        const signed char* wg = wtq + ((size_t)e << 20) + (size_t)n0 * K_DIM;

        // epilogue scalars (fly during the whole GEMM; in-order vmcnt
        // retirement keeps the prologue vmcnt(8) semantics intact)
        float sc[4], pt[16];
#pragma unroll
        for (int j = 0; j < 4; ++j)
            sc[j] = scale[e * N_DIM + n0 + wn + j * 16 + row_a];
#pragma unroll
        for (int i = 0; i < 4; ++i)
#pragma unroll
            for (int r = 0; r < 4; ++r)
                pt[i * 4 + r] = pts[m0 + wm + i * 16 + quad * 4 + r];

        v4i acc[4][4];
#pragma unroll
        for (int i = 0; i < 4; ++i)
#pragma unroll
            for (int j = 0; j < 4; ++j)
                acc[i][j] = (v4i){0, 0, 0, 0};

        auto stage = [&](int t, int b) {   // 8 global_load_lds per thread
            const int kb = t * BK;
            signed char* Ad = smem + b * 16384;
            signed char* Bd = smem + 32768 + b * 16384;
#pragma unroll
            for (int s = 0; s < 4; ++s) {
                const int c   = s * 4 + wv;        // chunk 0..15
                const int row = c * 8 + st_r;      // 0..127
                __builtin_amdgcn_global_load_lds(
                    (const __attribute__((address_space(1))) void*)
                        (xg + (size_t)row * K_DIM + kb + st_c),
                    (__attribute__((address_space(3))) void*)(Ad + c * 1024),
                    16, 0, 0);
                __builtin_amdgcn_global_load_lds(
                    (const __attribute__((address_space(1))) void*)
                        (wg + (size_t)row * K_DIM + kb + st_c),
                    (__attribute__((address_space(3))) void*)(Bd + c * 1024),
                    16, 0, 0);
            }
        };

        // prologue: two tiles in flight, wait only for tile 0
        stage(0, 0);
        stage(1, 1);
        asm volatile("s_waitcnt vmcnt(8)" ::: "memory");   // my tile-0 loads done
        __builtin_amdgcn_sched_barrier(0);
        __builtin_amdgcn_s_barrier();                      // everyone's tile 0 in LDS

        for (int t = 0; t < KSTEPS; ++t) {
            const int cur = t & 1;
            const signed char* Ab = smem + cur * 16384;
            const signed char* Bb = smem + 32768 + cur * 16384;

#pragma unroll
            for (int w = 0; w < 2; ++w) {                // two K=64 windows
                const int sa = ((w << 2) + quad) ^ rx;   // swizzled 16B slot
                v4i af[4], bf[4];
#pragma unroll
                for (int i = 0; i < 4; ++i)
                    af[i] = *(const v4i*)(Ab + (wm + i * 16 + row_a) * BK + sa * 16);
#pragma unroll
                for (int j = 0; j < 4; ++j)
                    bf[j] = *(const v4i*)(Bb + (wn + j * 16 + row_a) * BK + sa * 16);
#pragma unroll
                for (int i = 0; i < 4; ++i)
#pragma unroll
                    for (int j = 0; j < 4; ++j)
                        acc[i][j] = __builtin_amdgcn_mfma_i32_16x16x64_i8(
                            af[i], bf[j], acc[i][j], 0, 0, 0);
            }

            // (a) my ds_reads of buf[cur] done (lgkm) -> cur freeable;
            // (b) my stage(t+1) landed (vmcnt(0): only t+1 outstanding,
            //     stage(t+2) is issued post-barrier). One barrier
            // certifies both for the whole block.
            asm volatile("s_waitcnt vmcnt(0) lgkmcnt(0)" ::: "memory");
            __builtin_amdgcn_sched_barrier(0);
            __builtin_amdgcn_s_barrier();

            if (t + 2 < KSTEPS) {
                stage(t + 2, cur);                       // refill freed buffer
                __builtin_amdgcn_sched_barrier(0);       // keep VMEM issue
            }                                            // ahead of next ds_reads
        }

        // epilogue: direct dequant + segment-masked stores (round-0-proven;
        // WRITE_SIZE measured identical to the LDS-bounce path). No LDS
        // touched after the last loop barrier -> no end-of-expert barrier.
#pragma unroll
        for (int i = 0; i < 4; ++i) {
            const int rb = m0 + wm + i * 16 + quad * 4;
#pragma unroll
            for (int j = 0; j < 4; ++j) {
                const int c = n0 + wn + j * 16 + row_a;
#pragma unroll
                for (int r = 0; r < 4; ++r) {
                    const int rr = rb + r;
                    if (rr >= slo && rr < shi)
                        out[(size_t)rr * N_DIM + c] =
                            (float)acc[i][j][r] * sc[j] * pt[i * 4 + r];
                }
            }
        }
    }
}

// ---------------------------------------------------------------------------
extern "C" void kernel_launch(void* const* d_in, const int* in_sizes, int n_in,
                              void* d_out, int out_size, void* d_ws, size_t ws_size,
                              hipStream_t stream) {
    const int*   x     = (const int*)d_in[0];
    const int*   w     = (const int*)d_in[1];
    const float* scale = (const float*)d_in[2];
    const float* pts   = (const float*)d_in[3];
    const int*   g32   = (const int*)d_in[4];   // int32 or int64 -- sniffed in-kernel
    float*       out   = (float*)d_out;

    signed char* xq  = (signed char*)d_ws;                 // 32 MB
    signed char* wtq = xq + (size_t)M_DIM * K_DIM;         // 8 MB

    pack_x_kernel<<<M_DIM * K_DIM / 4 / 1024, 256, 0, stream>>>(
        (const int4*)x, (int*)xq);

    pack_wt_kernel<<<dim3(N_DIM / 64, K_DIM / 256, E_NUM), 256, 0, stream>>>(
        w, (int*)wtq);

    gmm_kernel<<<(M_DIM / BM) * (N_DIM / BN), 256, 0, stream>>>(
        xq, wtq, scale, pts, g32, out);
}

// Round 9
// 322.455 us; speedup vs baseline: 1.0267x; 1.0267x over previous
//
#include <hip/hip_runtime.h>

// Problem constants (fixed by the reference): E=8, M=32768, K=1024, N=1024
#define M_DIM 32768
#define K_DIM 1024
#define N_DIM 1024
#define E_NUM 8

#define BM 128
#define BN 128
#define BK 64             // m97/m103-proven: 32KB LDS dbuf -> 4 blocks/CU
#define KSTEPS (K_DIM / BK)   // 16

typedef __attribute__((ext_vector_type(4))) int v4i;

// ---------------------------------------------------------------------------
// Pass 1a: pack x (int32 valued int8) -> int8 [M][K].  (round-7 known-good)
// ---------------------------------------------------------------------------
__global__ __launch_bounds__(256) void pack_x_kernel(const int4* __restrict__ x,
                                                     int* __restrict__ xq) {
    const int base = blockIdx.x * 1024 + (threadIdx.x >> 6) * 256 + (threadIdx.x & 63);
#pragma unroll
    for (int k = 0; k < 4; ++k) {
        const int4 a = x[base + k * 64];
        xq[base + k * 64] =
            (a.x & 255) | ((a.y & 255) << 8) | ((a.z & 255) << 16) | (a.w << 24);
    }
}

// ---------------------------------------------------------------------------
// Pass 1b: pack + transpose weight [E][K][N] int32 -> [E][N][K] int8.
// (round-7 known-good)
// ---------------------------------------------------------------------------
__global__ __launch_bounds__(256) void pack_wt_kernel(const int* __restrict__ w,
                                                      int* __restrict__ wt) {
    __shared__ signed char tile[64][260];   // [n][k], +4 pad keeps banks spread
    const int e    = blockIdx.z;
    const int n0   = blockIdx.x * 64;
    const int k0   = blockIdx.y * 256;
    const int tid  = threadIdx.x;
    const int lane = tid & 63;
    const int wv   = tid >> 6;

    const int* wp = w + ((size_t)e << 20);
#pragma unroll 4
    for (int i = 0; i < 64; ++i) {
        const int k = wv * 64 + i;          // each wave: 64 k-rows
        tile[lane][k] = (signed char)wp[(size_t)(k0 + k) * N_DIM + n0 + lane];
    }
    __syncthreads();

    int* wo = wt + ((size_t)e << 18);       // int units: 1MB/4 per expert
#pragma unroll
    for (int i = 0; i < 16; ++i) {
        const int n = i * 4 + wv;
        const int v = *(const int*)&tile[n][lane * 4];   // 260 % 4 == 0, aligned
        wo[(size_t)(n0 + n) * (K_DIM / 4) + (k0 >> 2) + lane] = v;
    }
}

// ---------------------------------------------------------------------------
// Pass 2: grouped int8 GEMM + fused dequant.
// Round-9: round-2's two-barrier counted-vmcnt K-step (round 8 proved the
// single-barrier merge drains the VMEM queue -> -10%; stage MUST be issued
// before the counted wait), direct-store epilogue (round-8-proven: conflicts
// 0, WRITE identical), and BK=64 per m132/m97: 32KB LDS dbuf -> 4 blocks/CU
// at 128 VGPR (natural allocation, NO occupancy forcing -- round 4's forced
// (256,4) triggered a 64-VGPR spill recompile).
// BK=64 swizzle: 64B rows = 16 banks, so slot map s^(r&3) aliases rows r and
// r+4 (4-way). Fixed: s ^ ((r>>1)&3) -> same-parity rows spread over 4
// bank-groups x2 = 2-way = free (m136).
// ---------------------------------------------------------------------------
__global__ __launch_bounds__(256, 2) void gmm_kernel(
    const signed char* __restrict__ xq,    // [M][K] int8
    const signed char* __restrict__ wtq,   // [E][N][K] int8
    const float* __restrict__ scale,       // [E][N]
    const float* __restrict__ pts,         // [M]
    const int* __restrict__ g32,           // group_list viewed as int32
    float* __restrict__ out)               // [M][N] fp32
{
    // A(b) = smem + b*8KB, B(b) = smem + 16KB + b*8KB
    __shared__ signed char smem[32768];

    const int tid  = threadIdx.x;
    const int lane = tid & 63;
    const int wv   = tid >> 6;             // wave 0..3
    const int gid  = blockIdx.x;

    // XCD-stripe mapping: xcd = gid&7 owns contiguous 4096 m-rows, n inner
    // -> per-XCD A working set 4MB (L2-resident). FETCH 166->58MB confirmed.
    const int xcd   = gid & 7;
    const int local = gid >> 3;
    const int m0    = (xcd * 32 + (local >> 3)) * BM;
    const int n0    = (local & 7) * BN;

    // group_list (dtype-robust)
    const bool g_is_i64 = (g32[7] != M_DIM);
    int cum[E_NUM];
#pragma unroll
    for (int e = 0; e < E_NUM; ++e)
        cum[e] = g_is_i64 ? g32[2 * e] : g32[e];
    int e0 = 0;
    while (e0 < E_NUM - 1 && cum[e0] <= m0) ++e0;
    int e1 = 0;
    while (e1 < E_NUM - 1 && cum[e1] <= m0 + BM - 1) ++e1;

    const int wm    = (wv >> 1) * 64;
    const int wn    = (wv & 1) * 64;
    const int row_a = lane & 15;
    const int quad  = lane >> 4;
    // frag k-slot swizzle: global slot q of row r lives at LDS slot
    // q ^ ((r&15)>>1 & 3); row_a == r mod 16 for all frag rows.
    const int sa    = (quad ^ ((row_a >> 1) & 3)) * 16;

    // staging lane geometry: chunk = 16 rows x 64B = 1KB per wave-load.
    const int st_r = lane >> 2;                     // row in chunk 0..15
    const int st_c = ((lane & 3) ^ ((st_r >> 1) & 3)) * 16;  // swizzled src slot

    const signed char* xg = xq + (size_t)m0 * K_DIM;

    for (int e = e0; e <= e1; ++e) {
        const int lo = (e == 0) ? 0 : cum[e - 1];
        const int hi = cum[e];
        if (hi <= lo) continue;            // block-uniform
        const int slo = lo > m0 ? lo : m0;
        const int shi = hi < m0 + BM ? hi : m0 + BM;
        if (slo >= shi) continue;

        const signed char* wg = wtq + ((size_t)e << 20) + (size_t)n0 * K_DIM;

        // epilogue scalars (fly during the whole GEMM)
        float sc[4], pt[16];
#pragma unroll
        for (int j = 0; j < 4; ++j)
            sc[j] = scale[e * N_DIM + n0 + wn + j * 16 + row_a];
#pragma unroll
        for (int i = 0; i < 4; ++i)
#pragma unroll
            for (int r = 0; r < 4; ++r)
                pt[i * 4 + r] = pts[m0 + wm + i * 16 + quad * 4 + r];

        v4i acc[4][4];
#pragma unroll
        for (int i = 0; i < 4; ++i)
#pragma unroll
            for (int j = 0; j < 4; ++j)
                acc[i][j] = (v4i){0, 0, 0, 0};

        auto stage = [&](int t, int b) {   // 4 global_load_lds per thread
            const int kb = t * BK;
            signed char* Ad = smem + b * 8192;
            signed char* Bd = smem + 16384 + b * 8192;
#pragma unroll
            for (int g = 0; g < 2; ++g) {
                const int c   = g * 4 + wv;        // chunk 0..7
                const int row = c * 16 + st_r;     // 0..127
                __builtin_amdgcn_global_load_lds(
                    (const __attribute__((address_space(1))) void*)
                        (xg + (size_t)row * K_DIM + kb + st_c),
                    (__attribute__((address_space(3))) void*)(Ad + c * 1024),
                    16, 0, 0);
                __builtin_amdgcn_global_load_lds(
                    (const __attribute__((address_space(1))) void*)
                        (wg + (size_t)row * K_DIM + kb + st_c),
                    (__attribute__((address_space(3))) void*)(Bd + c * 1024),
                    16, 0, 0);
            }
        };

        // prologue: two tiles in flight, wait only for tile 0
        stage(0, 0);
        stage(1, 1);
        asm volatile("s_waitcnt vmcnt(4)" ::: "memory");   // my tile-0 loads done
        __builtin_amdgcn_sched_barrier(0);
        __builtin_amdgcn_s_barrier();                      // everyone's tile 0 in LDS

        for (int t = 0; t < KSTEPS; ++t) {
            const int cur = t & 1;
            const signed char* Ab = smem + cur * 8192;
            const signed char* Bb = smem + 16384 + cur * 8192;

            v4i af[4], bf[4];
#pragma unroll
            for (int i = 0; i < 4; ++i)
                af[i] = *(const v4i*)(Ab + (wm + i * 16 + row_a) * BK + sa);
#pragma unroll
            for (int j = 0; j < 4; ++j)
                bf[j] = *(const v4i*)(Bb + (wn + j * 16 + row_a) * BK + sa);
#pragma unroll
            for (int i = 0; i < 4; ++i)
#pragma unroll
                for (int j = 0; j < 4; ++j)
                    acc[i][j] = __builtin_amdgcn_mfma_i32_16x16x64_i8(
                        af[i], bf[j], acc[i][j], 0, 0, 0);

            // drain this tile's ds_reads BEFORE freeing cur for overwrite
            asm volatile("s_waitcnt lgkmcnt(0)" ::: "memory");
            __builtin_amdgcn_sched_barrier(0);
            __builtin_amdgcn_s_barrier();                // all waves done w/ cur

            if (t + 2 < KSTEPS) stage(t + 2, cur);       // issue BEFORE the wait
            if (t + 1 < KSTEPS) {
                if (t + 2 < KSTEPS)
                    asm volatile("s_waitcnt vmcnt(4)" ::: "memory"); // t+1 landed
                else
                    asm volatile("s_waitcnt vmcnt(0)" ::: "memory"); // last tile
                __builtin_amdgcn_sched_barrier(0);
                __builtin_amdgcn_s_barrier();            // visible to all waves
            }
        }

        // epilogue: direct dequant + segment-masked stores (round-8-proven:
        // conflicts 0, WRITE identical to the bounce path)
#pragma unroll
        for (int i = 0; i < 4; ++i) {
            const int rb = m0 + wm + i * 16 + quad * 4;
#pragma unroll
            for (int j = 0; j < 4; ++j) {
                const int c = n0 + wn + j * 16 + row_a;
#pragma unroll
                for (int r = 0; r < 4; ++r) {
                    const int rr = rb + r;
                    if (rr >= slo && rr < shi)
                        out[(size_t)rr * N_DIM + c] =
                            (float)acc[i][j][r] * sc[j] * pt[i * 4 + r];
                }
            }
        }
        // end-of-expert drain: next expert's prologue vmcnt(4) must not be
        // satisfied by retired epilogue stores (mixed load/store vmcnt
        // ordering is not guaranteed). Rare path (~6% of blocks).
        asm volatile("s_waitcnt vmcnt(0) lgkmcnt(0)" ::: "memory");
        __builtin_amdgcn_sched_barrier(0);
        __builtin_amdgcn_s_barrier();
    }
}

// ---------------------------------------------------------------------------
extern "C" void kernel_launch(void* const* d_in, const int* in_sizes, int n_in,
                              void* d_out, int out_size, void* d_ws, size_t ws_size,
                              hipStream_t stream) {
    const int*   x     = (const int*)d_in[0];
    const int*   w     = (const int*)d_in[1];
    const float* scale = (const float*)d_in[2];
    const float* pts   = (const float*)d_in[3];
    const int*   g32   = (const int*)d_in[4];   // int32 or int64 -- sniffed in-kernel
    float*       out   = (float*)d_out;

    signed char* xq  = (signed char*)d_ws;                 // 32 MB
    signed char* wtq = xq + (size_t)M_DIM * K_DIM;         // 8 MB

    pack_x_kernel<<<M_DIM * K_DIM / 4 / 1024, 256, 0, stream>>>(
        (const int4*)x, (int*)xq);

    pack_wt_kernel<<<dim3(N_DIM / 64, K_DIM / 256, E_NUM), 256, 0, stream>>>(
        w, (int*)wtq);

    gmm_kernel<<<(M_DIM / BM) * (N_DIM / BN), 256, 0, stream>>>(
        xq, wtq, scale, pts, g32, out);
}